// Round 1
// baseline (80.699 us; speedup 1.0000x reference)
//
#include <hip/hip_runtime.h>

// CARAFE naive upsample: N=2, C=256, H=100, W=100, K=5, G=1, S=2.
// out[n,c,2h+a,2w+b] = sum_{dy,dx} mask[n,dy*5+dx,2h+a,2w+b] * feat[n,c,h+dy-2,w+dx-2]
// (zero-padded features outside [0,H)x[0,W)).
//
// Thread -> one low-res pixel (h,w) x 8-channel chunk -> computes the 2x2
// output quad for those 8 channels. Mask loads (4 per tap, as 2x float2)
// amortized over 8 channels; feature loads (8 per tap) reused over 4 outputs.

#define N_ 2
#define C_ 256
#define H_ 100
#define W_ 100
#define KK_ 25
#define CC 8
#define HW_ (H_ * W_)
#define OW_ (W_ * 2)
#define OHW_ (HW_ * 4)
#define NCHUNK (C_ / CC)
#define SPATIAL_BLOCKS ((HW_ + 255) / 256)   // 40

__global__ __launch_bounds__(256) void carafe_kernel(
    const float* __restrict__ feat,
    const float* __restrict__ mask,
    float* __restrict__ out) {

    int b = blockIdx.x;
    int sb = b % SPATIAL_BLOCKS;
    int rest = b / SPATIAL_BLOCKS;
    int cchunk = rest % NCHUNK;
    int n = rest / NCHUNK;

    int idx = sb * 256 + threadIdx.x;
    if (idx >= HW_) return;
    int h = idx / W_;
    int w = idx % W_;
    int c0 = cchunk * CC;

    float acc[CC][4];
#pragma unroll
    for (int c = 0; c < CC; ++c) {
        acc[c][0] = 0.f; acc[c][1] = 0.f; acc[c][2] = 0.f; acc[c][3] = 0.f;
    }

    const float* mbase = mask + (size_t)n * KK_ * OHW_;
    const float* fbase = feat + ((size_t)n * C_ + c0) * HW_;

    const int oh0 = 2 * h;
    const int ow0 = 2 * w;

#pragma unroll
    for (int tap = 0; tap < KK_; ++tap) {
        const int dy = tap / 5;
        const int dx = tap % 5;
        const int y = h + dy - 2;
        const int x = w + dx - 2;
        const bool valid = (y >= 0) & (y < H_) & (x >= 0) & (x < W_);

        const float* mrow = mbase + (size_t)tap * OHW_ + (size_t)oh0 * OW_ + ow0;
        float2 m0 = *reinterpret_cast<const float2*>(mrow);          // a=0, b=0..1
        float2 m1 = *reinterpret_cast<const float2*>(mrow + OW_);    // a=1, b=0..1

        const int foff = y * W_ + x;
#pragma unroll
        for (int c = 0; c < CC; ++c) {
            float f = valid ? fbase[(size_t)c * HW_ + foff] : 0.f;
            acc[c][0] += f * m0.x;
            acc[c][1] += f * m0.y;
            acc[c][2] += f * m1.x;
            acc[c][3] += f * m1.y;
        }
    }

    float* obase = out + ((size_t)n * C_ + c0) * (size_t)OHW_
                 + (size_t)oh0 * OW_ + ow0;
#pragma unroll
    for (int c = 0; c < CC; ++c) {
        float2 r0 = make_float2(acc[c][0], acc[c][1]);
        float2 r1 = make_float2(acc[c][2], acc[c][3]);
        *reinterpret_cast<float2*>(obase + (size_t)c * OHW_) = r0;
        *reinterpret_cast<float2*>(obase + (size_t)c * OHW_ + OW_) = r1;
    }
}

extern "C" void kernel_launch(void* const* d_in, const int* in_sizes, int n_in,
                              void* d_out, int out_size, void* d_ws, size_t ws_size,
                              hipStream_t stream) {
    const float* feat = (const float*)d_in[0];
    const float* mask = (const float*)d_in[1];
    float* out = (float*)d_out;

    const int grid = N_ * NCHUNK * SPATIAL_BLOCKS;  // 2 * 32 * 40 = 2560
    carafe_kernel<<<grid, 256, 0, stream>>>(feat, mask, out);
}